// Round 11
// baseline (4851.426 us; speedup 1.0000x reference)
//
#include <hip/hip_runtime.h>
#include <hip/hip_bf16.h>
#include <math.h>

#define DM   1024
#define DF   4096
#define NH   8
#define NB   4
#define NS   2048
#define MT   (NB*NS)   // 8192 tokens
#define MQ   2048      // M-split quarter
#define KC   4096      // gemm2 K-split chunk
#define NKS  8         // gemm2 K-splits

typedef __bf16 bf16;
typedef __bf16 bf16x4 __attribute__((ext_vector_type(4)));
typedef __bf16 bf16x8 __attribute__((ext_vector_type(8)));
typedef float  f32x4  __attribute__((ext_vector_type(4)));

typedef __attribute__((address_space(3))) unsigned int u32_lds;
typedef const __attribute__((address_space(1))) void cv_glob;

__device__ __forceinline__ void gload16(const void* g, const void* l) {
    __builtin_amdgcn_global_load_lds(
        (cv_glob*)(unsigned long long)g,
        (u32_lds*)(unsigned int)(unsigned long long)l,
        16, 0, 0);
}

// tanh-form GELU: |gelu_tanh - gelu_erf| <= ~2e-3 absolute; 3x cheaper than erff.
__device__ __forceinline__ float gelu_f(float x) {
    float u = -1.5957691216057308f * fmaf(0.044715f * x, x * x, x);
    return x * __builtin_amdgcn_rcpf(1.f + __expf(u));
}

// SWIZZLE CONVENTION (T2, both-sides): every bf16 buffer consumed by GEMM staging is
// stored with 16B chunks permuted within each 128B (64-elem) row-block:
// elem e of row r stored at e ^ ((r&7)<<3). gload_lds copies linearly; ds_read
// XORs byte ^ ((row&7)<<4). Proven R2-R10: SQ_LDS_BANK_CONFLICT == 0.

// ---------------- x f32 -> bf16 (swizzled rows = tokens) ----------------
__global__ __launch_bounds__(256) void k_cvtx(const float* __restrict__ in, bf16* __restrict__ out) {
    long i = ((long)blockIdx.x * 256 + threadIdx.x) * 8;
    float4 a = *(const float4*)(in + i);
    float4 b = *(const float4*)(in + i + 4);
    bf16x8 o;
    o[0]=(bf16)a.x; o[1]=(bf16)a.y; o[2]=(bf16)a.z; o[3]=(bf16)a.w;
    o[4]=(bf16)b.x; o[5]=(bf16)b.y; o[6]=(bf16)b.z; o[7]=(bf16)b.w;
    long t7 = (i >> 10) & 7;
    *(bf16x8*)(out + (i ^ (t7 << 3))) = o;
}

// ---- transpose+convert+swizzle, 64x64 tile: out[c][r ^ ((c&7)<<3)] = (bf16)in[r*C+c] ----
__global__ __launch_bounds__(256) void k_tcvt2(const float* __restrict__ in, bf16* __restrict__ out,
                                               int C, long outStride, long inBatch, long outBatch) {
    __shared__ float t[64][65];
    const float* ip = in + (long)blockIdx.z * inBatch;
    bf16* op = out + (long)blockIdx.z * outBatch;
    const int c0 = blockIdx.x * 64, r0 = blockIdx.y * 64;
    const int tid = threadIdx.x;
    const int rr = tid >> 4, cc = tid & 15;
    #pragma unroll
    for (int it = 0; it < 4; ++it) {
        const int r = rr + 16 * it;
        float4 v = *(const float4*)(ip + (long)(r0 + r) * C + c0 + cc * 4);
        t[r][cc*4+0] = v.x; t[r][cc*4+1] = v.y; t[r][cc*4+2] = v.z; t[r][cc*4+3] = v.w;
    }
    __syncthreads();
    #pragma unroll
    for (int it = 0; it < 2; ++it) {
        const int oc = (tid >> 3) + 32 * it;
        const int e0 = (tid & 7) * 8;
        bf16 tmp[8];
        #pragma unroll
        for (int j = 0; j < 8; ++j) tmp[j] = (bf16)t[e0 + j][oc];
        const int rs = e0 ^ ((oc & 7) << 3);
        *(bf16x8*)(op + (long)(c0 + oc) * outStride + r0 + rs) = *(bf16x8*)tmp;
    }
}

// ---------------- state projection: sp[b][d] = rs[b]@Ws[:,d] + bs[d] ----------------
__global__ __launch_bounds__(256) void k_sproj2(const float* __restrict__ rs, const float* __restrict__ Ws,
                                                const float* __restrict__ bs, float* __restrict__ sp) {
    const int d0 = blockIdx.x * 16;
    const int ks = threadIdx.x >> 4, dd = threadIdx.x & 15;
    const float* r = rs + blockIdx.y * DM;
    float acc = 0.f;
    #pragma unroll 4
    for (int k = ks * 64; k < ks * 64 + 64; ++k)
        acc += r[k] * Ws[(long)k * DM + d0 + dd];
    __shared__ float red[256];
    red[threadIdx.x] = acc;
    __syncthreads();
    if (threadIdx.x < 16) {
        float v = bs[d0 + threadIdx.x];
        #pragma unroll
        for (int s = 0; s < 16; ++s) v += red[threadIdx.x + 16 * s];
        sp[blockIdx.y * DM + d0 + threadIdx.x] = v;
    }
}

// ---------------- gate: logits = g@Wg + bg; softmax -> wout [t][8] ----------------
__global__ __launch_bounds__(256) void k_gate(const bf16* __restrict__ g, const float* __restrict__ Wg,
                                              const float* __restrict__ bg, float* __restrict__ wout) {
    int lane = threadIdx.x & 63, wid = threadIdx.x >> 6;
    long t = (long)blockIdx.x * 4 + wid;
    const bf16* gr = g + t * DM + lane * 16;
    bf16x8 v0 = *(const bf16x8*)gr;
    bf16x8 v1 = *(const bf16x8*)(gr + 8);
    float s0=0,s1=0,s2=0,s3=0,s4=0,s5=0,s6=0,s7=0;
    #pragma unroll
    for (int i = 0; i < 16; ++i) {
        float gv = (float)((i < 8) ? v0[i] : v1[i - 8]);
        const float4* wr = (const float4*)(Wg + (long)(lane * 16 + i) * NH);
        float4 wa = wr[0], wb = wr[1];
        s0 += gv*wa.x; s1 += gv*wa.y; s2 += gv*wa.z; s3 += gv*wa.w;
        s4 += gv*wb.x; s5 += gv*wb.y; s6 += gv*wb.z; s7 += gv*wb.w;
    }
    #pragma unroll
    for (int off = 32; off >= 1; off >>= 1) {
        s0 += __shfl_xor(s0, off); s1 += __shfl_xor(s1, off);
        s2 += __shfl_xor(s2, off); s3 += __shfl_xor(s3, off);
        s4 += __shfl_xor(s4, off); s5 += __shfl_xor(s5, off);
        s6 += __shfl_xor(s6, off); s7 += __shfl_xor(s7, off);
    }
    float l0=s0+bg[0], l1=s1+bg[1], l2=s2+bg[2], l3=s3+bg[3];
    float l4=s4+bg[4], l5=s5+bg[5], l6=s6+bg[6], l7=s7+bg[7];
    float m = fmaxf(fmaxf(fmaxf(l0,l1),fmaxf(l2,l3)), fmaxf(fmaxf(l4,l5),fmaxf(l6,l7)));
    float e0=expf(l0-m), e1=expf(l1-m), e2=expf(l2-m), e3=expf(l3-m);
    float e4=expf(l4-m), e5=expf(l5-m), e6=expf(l6-m), e7=expf(l7-m);
    float inv = 1.f / (e0+e1+e2+e3+e4+e5+e6+e7);
    if (lane == 0) {
        float* wo = wout + t * NH;
        wo[0]=e0*inv; wo[1]=e1*inv; wo[2]=e2*inv; wo[3]=e3*inv;
        wo[4]=e4*inv; wo[5]=e5*inv; wo[6]=e6*inv; wo[7]=e7*inv;
    }
}

// ============ 256x256x64 bf16 GEMM — 16 waves, one-phase-ahead operands (counted lgkm) ============
// R9 geometry (proven best): 16 waves 4Mx4N, wave out 64x64, acc[4][4] (AGPR), LDS A 3x32K +
// B 2x32K = 160 KB, stages B(t+1)/A(t+2), boundary vmcnt(2).
// NEW K-loop: operand sets X (kk=0) / Y (kk=1) are read ONE PHASE AHEAD of their MFMA, so the
// wait before each MFMA cluster is a counted lgkmcnt(8) (the 8 newer reads stay in flight) and
// the DS queue never drains — breaks the read/MFMA phase-lock that held R5-R10 at ~6.4k cy/tile
// (DS pipe is the binding resource: 256 b128-ops/tile ≈ 3.1k cy; goal = 100% DS duty).
//   prologue: stage A0,B0,A1; vmcnt(2); barrier; READ X(0)
//   loop t:  READ Y(t) ; lgkm(8)[X ready, all older retired] ; barrier#1 ;
//            stage B(t+1), A(t+2)  [safe: those bufs last read at t-1, retired chip-wide] ;
//            MFMA(X) ; vmcnt(2)[A(t+1),B(t+1) retired; A(t+2) in flight] ; barrier#2 ;
//            READ X(t+1) ; lgkm(8)[Y ready] ; MFMA(Y)
// Race-free by ledger (no in-flight read targets a buffer being staged). Tail: reads/stages
// clamp to the last tile (results unused; keeps waitcnt ledger and barrier counts uniform).
// MAP (proven R7): 1 = gemm1 XCD-rectangle; 2 = gemm2 one-K-chunk-per-XCD.
// EPI 0: gelu(acc+bias[col]+sp[t>>11][col])        -> bf16 outH (unswizzled)
// EPI 1: w[t][col>>12]*gelu(acc+bias[col])         -> bf16 outH (swizzled)
// EPI 2: bz==0: acc+sum_h w*b2 -> outF ; bz>0: acc -> parts[bz-1]
template<int EPI, int MAP>
__global__ __launch_bounds__(1024, 4) void k_g2(
    const bf16* __restrict__ A, long lda,
    const bf16* __restrict__ Bt, long ldb,
    int K, long kcs, int gm, int gn,
    bf16* __restrict__ outH, float* __restrict__ outF, long ldc,
    const float* __restrict__ bias,
    const float* __restrict__ aux1, const float* __restrict__ aux2,
    float* __restrict__ parts, long pStride)
{
    __shared__ __align__(16) unsigned char lsA[3][32 * 1024];
    __shared__ __align__(16) unsigned char lsB[2][32 * 1024];
    const int tid = threadIdx.x, lane = tid & 63, wid = tid >> 6;

    const int id = blockIdx.x;
    int bx, by, bz;
    if (MAP == 1) {            // grid 1024 = 8bx x 128by, rounds of 256
        const int x = id & 7, j = (id >> 3) & 31, r = id >> 8;
        bx = (x & 1) * 4 + (j & 3);
        by = (x >> 1) * 8 + (j >> 2) + r * 32;
        bz = 0;
    } else if (MAP == 2) {     // grid 256 = 8bx x 4by x 8bz
        bz = id & 7;
        bx = (id >> 3) & 7;
        by = id >> 6;
    } else {
        bx = id % gm; by = (id / gm) % gn; bz = id / (gm * gn);
    }
    const long tileM = (long)bx * 256;
    const long tileN = (long)by * 256;
    const bf16* Ab = A + tileM * lda + (long)bz * kcs;
    const bf16* Bb = Bt + tileN * ldb + (long)bz * kcs;

    const int wr = wid >> 2, wc = wid & 3;      // 4 x 4 waves, wave out 64x64
    const int l15 = lane & 15, kd = lane >> 4;
    const int swz = (lane & 7) << 4;

    f32x4 acc[4][4];
    #pragma unroll
    for (int m = 0; m < 4; ++m)
        #pragma unroll
        for (int n = 0; n < 4; ++n) { f32x4 z = {0.f,0.f,0.f,0.f}; acc[m][n] = z; }

    auto STAGE_A = [&](int t, int buf) {
        const long kO = (long)t * 64;
        #pragma unroll
        for (int is = 0; is < 2; ++is) {
            const int o = is * 16384 + tid * 16;
            gload16(Ab + (long)(o >> 7) * lda + kO + ((o & 127) >> 1), lsA[buf] + o);
        }
    };
    auto STAGE_B = [&](int t, int buf) {
        const long kO = (long)t * 64;
        #pragma unroll
        for (int is = 0; is < 2; ++is) {
            const int o = is * 16384 + tid * 16;
            gload16(Bb + (long)(o >> 7) * ldb + kO + ((o & 127) >> 1), lsB[buf] + o);
        }
    };

#define READ_SET(AV, BV, AS, BS, KK) \
    { const int kb = ((KK) * 64 + kd * 16) ^ swz; \
      _Pragma("unroll") for (int m = 0; m < 4; ++m) \
          AV[m] = *(const bf16x8*)((AS) + ((wr * 64 + m * 16 + l15) << 7) + kb); \
      _Pragma("unroll") for (int n = 0; n < 4; ++n) \
          BV[n] = *(const bf16x8*)((BS) + ((wc * 64 + n * 16 + l15) << 7) + kb); }
#define MFMA_SET(AV, BV) \
    __builtin_amdgcn_s_setprio(1); \
    _Pragma("unroll") for (int m = 0; m < 4; ++m) \
    _Pragma("unroll") for (int n = 0; n < 4; ++n) \
        acc[m][n] = __builtin_amdgcn_mfma_f32_16x16x32_bf16(AV[m], BV[n], acc[m][n], 0, 0, 0); \
    __builtin_amdgcn_s_setprio(0);
#define SBAR __builtin_amdgcn_sched_barrier(0)

    const int NT = K >> 6;                      // >= 16 at all call sites
    bf16x8 avX[4], bvX[4], avY[4], bvY[4];

    STAGE_A(0, 0); STAGE_B(0, 0); STAGE_A(1, 1);
    asm volatile("s_waitcnt vmcnt(2)" ::: "memory");
    __builtin_amdgcn_s_barrier();
    SBAR;
    READ_SET(avX, bvX, lsA[0], lsB[0], 0);      // X(0); DS outstanding = 8 entering loop
    SBAR;
    for (int t = 0; t < NT; ++t) {
        const unsigned char* As  = lsA[t % 3];
        const unsigned char* Bs  = lsB[t & 1];
        const unsigned char* Asn = lsA[(t + 1) % 3];
        const unsigned char* Bsn = lsB[(t + 1) & 1];
        const int ts1 = (t + 1 < NT) ? t + 1 : t;   // clamped stage/read sources (tail)
        const int ts2 = (t + 2 < NT) ? t + 2 : ts1;
        // ---- READ Y(t); counted wait retires X and everything older ----
        READ_SET(avY, bvY, As, Bs, 1);
        SBAR;
        asm volatile("s_waitcnt lgkmcnt(8)" ::: "memory");
        SBAR;
        __builtin_amdgcn_s_barrier();           // #1: all waves' pre-Y reads retired chip-wide
        SBAR;
        // ---- stage into buffers last read at t-1 (safe), then MFMA X ----
        STAGE_B(ts1, (t + 1) & 1);
        STAGE_A(ts2, (t + 2) % 3);
        SBAR;
        MFMA_SET(avX, bvX);
        SBAR;
        // ---- make tile t+1 resident; A(t+2) stays in flight ----
        asm volatile("s_waitcnt vmcnt(2)" ::: "memory");
        __builtin_amdgcn_s_barrier();           // #2
        SBAR;
        // ---- READ X(t+1); counted wait retires Y; MFMA Y ----
        READ_SET(avX, bvX, Asn, Bsn, 0);
        SBAR;
        asm volatile("s_waitcnt lgkmcnt(8)" ::: "memory");
        SBAR;
        MFMA_SET(avY, bvY);
        SBAR;
    }

    // epilogue: C/D layout col = lane&15, row = (lane>>4)*4 + j
    const long rowBase = tileM + wr * 64;
    const int  colBase = (int)tileN + wc * 64;
    #pragma unroll
    for (int m = 0; m < 4; ++m) {
        const long r0 = rowBase + m * 16 + (kd * 4);
        #pragma unroll
        for (int n = 0; n < 4; ++n) {
            const int col = colBase + n * 16 + l15;
            #pragma unroll
            for (int j = 0; j < 4; ++j) {
                const long tk = r0 + j;
                float v = acc[m][n][j];
                if constexpr (EPI == 0) {
                    v += bias[col] + aux1[(long)(tk >> 11) * DM + col];
                    v = gelu_f(v);
                    outH[tk * ldc + col] = (bf16)v;
                } else if constexpr (EPI == 1) {
                    v += bias[col];
                    v = gelu_f(v);
                    v *= aux1[tk * NH + (col >> 12)];
                    outH[tk * ldc + (col ^ (((int)tk & 7) << 3))] = (bf16)v;
                } else {
                    if (bz == 0) {
                        float bsum = 0.f;
                        #pragma unroll
                        for (int hh = 0; hh < NH; ++hh)
                            bsum += aux1[tk * NH + hh] * aux2[(long)hh * DM + col];
                        outF[tk * ldc + col] = v + bsum;
                    } else {
                        parts[(long)(bz - 1) * pStride + tk * ldc + col] = v;
                    }
                }
            }
        }
    }
#undef READ_SET
#undef MFMA_SET
#undef SBAR
}

// ---------------- reduce: out += sum of partials ----------------
__global__ __launch_bounds__(256) void k_red(float* __restrict__ out, const float* __restrict__ parts,
                                             long pStride, int np) {
    long i = ((long)blockIdx.x * 256 + threadIdx.x) * 4;
    float4 v = *(float4*)(out + i);
    #pragma unroll
    for (int p = 0; p < NKS - 1; ++p) {
        float4 q = *(const float4*)(parts + (long)p * pStride + i);
        v.x += q.x; v.y += q.y; v.z += q.z; v.w += q.w;
    }
    *(float4*)(out + i) = v;
    (void)np;
}

extern "C" void kernel_launch(void* const* d_in, const int* in_sizes, int n_in,
                              void* d_out, int out_size, void* d_ws, size_t ws_size,
                              hipStream_t stream)
{
    const float* x  = (const float*)d_in[0];
    const float* rs = (const float*)d_in[1];
    const float* W1 = (const float*)d_in[2];
    const float* b1 = (const float*)d_in[3];
    const float* W2 = (const float*)d_in[4];
    const float* b2 = (const float*)d_in[5];
    const float* Ws = (const float*)d_in[6];
    const float* bs = (const float*)d_in[7];
    const float* Wi = (const float*)d_in[8];
    const float* bi = (const float*)d_in[9];
    const float* Wg = (const float*)d_in[10];
    const float* bg = (const float*)d_in[11];

    float* out  = (float*)d_out;                    // [8192][1024] f32
    float* wout = out + (size_t)MT * DM;            // [8192][8]   f32 (output 1)

    unsigned char* ws = (unsigned char*)d_ws;
    size_t ofs = 0;
    auto alloc = [&](size_t bytes) { void* p = ws + ofs; ofs += (bytes + 255) & ~(size_t)255; return p; };

    bf16*  xbf  = (bf16*)alloc((size_t)MT * DM * 2);          // 16.8 MB (swizzled)
    bf16*  WiT  = (bf16*)alloc((size_t)DM * DM * 2);          //  2.1 MB (swizzled)
    bf16*  g    = (bf16*)alloc((size_t)MT * DM * 2);          // 16.8 MB (linear)
    float* sp   = (float*)alloc((size_t)NB * DM * 4);         // 16 KB
    bf16*  W1T  = (bf16*)alloc((size_t)NH * DF * DM * 2);     // 67.1 MB [hf][d] swizzled
    bf16*  W2T  = (bf16*)alloc((size_t)NH * DF * DM * 2);     // 67.1 MB [d][hf] swizzled
    bf16*  hp   = (bf16*)alloc((size_t)MQ * NH * DF * 2);     // 134.2 MB [t][hf] swizzled (per quarter)
    float* part = (float*)alloc((size_t)(NKS - 1) * MQ * DM * 4);  // 58.7 MB
    const long pStride = (long)MQ * DM;

    // stage 0: conversions / transposes / projections
    k_cvtx<<<(MT * DM) / (256 * 8), 256, 0, stream>>>(x, xbf);
    k_tcvt2<<<dim3(DM / 64, DM / 64, 1), 256, 0, stream>>>(Wi, WiT, DM, DM, 0, 0);
    k_sproj2<<<dim3(DM / 16, NB), 256, 0, stream>>>(rs, Ws, bs, sp);

    // stage 1: input proj -> gelu(combined) -> g, then gate weights
    k_g2<0, 0><<<(MT / 256) * (DM / 256), 1024, 0, stream>>>(
        xbf, DM, WiT, DM, DM, 0, MT / 256, DM / 256,
        g, nullptr, DM, bi, sp, nullptr, nullptr, 0);
    k_gate<<<MT / 4, 256, 0, stream>>>(g, Wg, bg, wout);

    // weight transposes
    k_tcvt2<<<dim3(DF / 64, DM / 64, NH), 256, 0, stream>>>(
        W1, W1T, DF, DM, (long)DM * DF, (long)DF * DM);
    k_tcvt2<<<dim3(DM / 64, DF / 64, NH), 256, 0, stream>>>(
        W2, W2T, DM, (long)NH * DF, (long)DF * DM, DF);

    // stage 2: per M-quarter: gemm1 (all heads) -> hp ; gemm2 (K-split 8) ; reduce
    for (int q = 0; q < MT / MQ; ++q) {
        const bf16*  xq = xbf + (size_t)q * MQ * DM;
        const float* wq = wout + (size_t)q * MQ * NH;
        float*       oq = out + (size_t)q * MQ * DM;
        k_g2<1, 1><<<(MQ / 256) * (NH * DF / 256), 1024, 0, stream>>>(
            xq, DM, W1T, DM, DM, 0, MQ / 256, NH * DF / 256,
            hp, nullptr, (long)NH * DF, b1, wq, nullptr, nullptr, 0);
        k_g2<2, 2><<<(MQ / 256) * (DM / 256) * NKS, 1024, 0, stream>>>(
            hp, (long)NH * DF, W2T, (long)NH * DF, KC, KC, MQ / 256, DM / 256,
            nullptr, oq, DM, nullptr, wq, b2, part, pStride);
        k_red<<<(MQ * DM) / (256 * 4), 256, 0, stream>>>(oq, part, pStride, NKS - 1);
    }
    (void)in_sizes; (void)n_in; (void)out_size;
}

// Round 12
// 1795.980 us; speedup vs baseline: 2.7013x; 2.7013x over previous
//
#include <hip/hip_runtime.h>
#include <hip/hip_bf16.h>
#include <math.h>

#define DM   1024
#define DF   4096
#define NH   8
#define NB   4
#define NS   2048
#define MT   (NB*NS)   // 8192 tokens
#define MQ   2048      // M-split quarter
#define KC   8192      // gemm2 K-split chunk
#define NKS  4         // gemm2 K-splits

typedef __bf16 bf16;
typedef __bf16 bf16x4 __attribute__((ext_vector_type(4)));
typedef __bf16 bf16x8 __attribute__((ext_vector_type(8)));
typedef float  f32x4  __attribute__((ext_vector_type(4)));

typedef __attribute__((address_space(3))) unsigned int u32_lds;
typedef const __attribute__((address_space(1))) void cv_glob;

__device__ __forceinline__ void gload16(const void* g, const void* l) {
    __builtin_amdgcn_global_load_lds(
        (cv_glob*)(unsigned long long)g,
        (u32_lds*)(unsigned int)(unsigned long long)l,
        16, 0, 0);
}

// tanh-form GELU: |gelu_tanh - gelu_erf| <= ~2e-3 absolute; 3x cheaper than erff.
__device__ __forceinline__ float gelu_f(float x) {
    float u = -1.5957691216057308f * fmaf(0.044715f * x, x * x, x);
    return x * __builtin_amdgcn_rcpf(1.f + __expf(u));
}

// SWIZZLE CONVENTION (T2, both-sides): every bf16 buffer consumed by GEMM staging is
// stored with 16B chunks permuted within each 128B (64-elem) row-block:
// elem e of row r stored at e ^ ((r&7)<<3). gload_lds copies linearly; ds_read
// XORs byte ^ ((row&7)<<4). Proven R2-R11: SQ_LDS_BANK_CONFLICT == 0.

// ---------------- x f32 -> bf16 (swizzled rows = tokens) ----------------
__global__ __launch_bounds__(256) void k_cvtx(const float* __restrict__ in, bf16* __restrict__ out) {
    long i = ((long)blockIdx.x * 256 + threadIdx.x) * 8;
    float4 a = *(const float4*)(in + i);
    float4 b = *(const float4*)(in + i + 4);
    bf16x8 o;
    o[0]=(bf16)a.x; o[1]=(bf16)a.y; o[2]=(bf16)a.z; o[3]=(bf16)a.w;
    o[4]=(bf16)b.x; o[5]=(bf16)b.y; o[6]=(bf16)b.z; o[7]=(bf16)b.w;
    long t7 = (i >> 10) & 7;
    *(bf16x8*)(out + (i ^ (t7 << 3))) = o;
}

// ---- transpose+convert+swizzle, 64x64 tile: out[c][r ^ ((c&7)<<3)] = (bf16)in[r*C+c] ----
__global__ __launch_bounds__(256) void k_tcvt2(const float* __restrict__ in, bf16* __restrict__ out,
                                               int C, long outStride, long inBatch, long outBatch) {
    __shared__ float t[64][65];
    const float* ip = in + (long)blockIdx.z * inBatch;
    bf16* op = out + (long)blockIdx.z * outBatch;
    const int c0 = blockIdx.x * 64, r0 = blockIdx.y * 64;
    const int tid = threadIdx.x;
    const int rr = tid >> 4, cc = tid & 15;
    #pragma unroll
    for (int it = 0; it < 4; ++it) {
        const int r = rr + 16 * it;
        float4 v = *(const float4*)(ip + (long)(r0 + r) * C + c0 + cc * 4);
        t[r][cc*4+0] = v.x; t[r][cc*4+1] = v.y; t[r][cc*4+2] = v.z; t[r][cc*4+3] = v.w;
    }
    __syncthreads();
    #pragma unroll
    for (int it = 0; it < 2; ++it) {
        const int oc = (tid >> 3) + 32 * it;
        const int e0 = (tid & 7) * 8;
        bf16 tmp[8];
        #pragma unroll
        for (int j = 0; j < 8; ++j) tmp[j] = (bf16)t[e0 + j][oc];
        const int rs = e0 ^ ((oc & 7) << 3);
        *(bf16x8*)(op + (long)(c0 + oc) * outStride + r0 + rs) = *(bf16x8*)tmp;
    }
}

// ---------------- state projection: sp[b][d] = rs[b]@Ws[:,d] + bs[d] ----------------
__global__ __launch_bounds__(256) void k_sproj2(const float* __restrict__ rs, const float* __restrict__ Ws,
                                                const float* __restrict__ bs, float* __restrict__ sp) {
    const int d0 = blockIdx.x * 16;
    const int ks = threadIdx.x >> 4, dd = threadIdx.x & 15;
    const float* r = rs + blockIdx.y * DM;
    float acc = 0.f;
    #pragma unroll 4
    for (int k = ks * 64; k < ks * 64 + 64; ++k)
        acc += r[k] * Ws[(long)k * DM + d0 + dd];
    __shared__ float red[256];
    red[threadIdx.x] = acc;
    __syncthreads();
    if (threadIdx.x < 16) {
        float v = bs[d0 + threadIdx.x];
        #pragma unroll
        for (int s = 0; s < 16; ++s) v += red[threadIdx.x + 16 * s];
        sp[blockIdx.y * DM + d0 + threadIdx.x] = v;
    }
}

// ---------------- gate: logits = g@Wg + bg; softmax -> wout [t][8] ----------------
__global__ __launch_bounds__(256) void k_gate(const bf16* __restrict__ g, const float* __restrict__ Wg,
                                              const float* __restrict__ bg, float* __restrict__ wout) {
    int lane = threadIdx.x & 63, wid = threadIdx.x >> 6;
    long t = (long)blockIdx.x * 4 + wid;
    const bf16* gr = g + t * DM + lane * 16;
    bf16x8 v0 = *(const bf16x8*)gr;
    bf16x8 v1 = *(const bf16x8*)(gr + 8);
    float s0=0,s1=0,s2=0,s3=0,s4=0,s5=0,s6=0,s7=0;
    #pragma unroll
    for (int i = 0; i < 16; ++i) {
        float gv = (float)((i < 8) ? v0[i] : v1[i - 8]);
        const float4* wr = (const float4*)(Wg + (long)(lane * 16 + i) * NH);
        float4 wa = wr[0], wb = wr[1];
        s0 += gv*wa.x; s1 += gv*wa.y; s2 += gv*wa.z; s3 += gv*wa.w;
        s4 += gv*wb.x; s5 += gv*wb.y; s6 += gv*wb.z; s7 += gv*wb.w;
    }
    #pragma unroll
    for (int off = 32; off >= 1; off >>= 1) {
        s0 += __shfl_xor(s0, off); s1 += __shfl_xor(s1, off);
        s2 += __shfl_xor(s2, off); s3 += __shfl_xor(s3, off);
        s4 += __shfl_xor(s4, off); s5 += __shfl_xor(s5, off);
        s6 += __shfl_xor(s6, off); s7 += __shfl_xor(s7, off);
    }
    float l0=s0+bg[0], l1=s1+bg[1], l2=s2+bg[2], l3=s3+bg[3];
    float l4=s4+bg[4], l5=s5+bg[5], l6=s6+bg[6], l7=s7+bg[7];
    float m = fmaxf(fmaxf(fmaxf(l0,l1),fmaxf(l2,l3)), fmaxf(fmaxf(l4,l5),fmaxf(l6,l7)));
    float e0=expf(l0-m), e1=expf(l1-m), e2=expf(l2-m), e3=expf(l3-m);
    float e4=expf(l4-m), e5=expf(l5-m), e6=expf(l6-m), e7=expf(l7-m);
    float inv = 1.f / (e0+e1+e2+e3+e4+e5+e6+e7);
    if (lane == 0) {
        float* wo = wout + t * NH;
        wo[0]=e0*inv; wo[1]=e1*inv; wo[2]=e2*inv; wo[3]=e3*inv;
        wo[4]=e4*inv; wo[5]=e5*inv; wo[6]=e6*inv; wo[7]=e7*inv;
    }
}

// ============ 256x128x64 bf16 GEMM — 8 waves, one-phase-ahead operands (fits registers) ============
// R11's counted-lgkm register pipeline at a geometry whose live set fits the 256-VGPR budget:
// 8 waves (4M x 2N), wave out 64x64, acc[4][4]=64 + X set 32 + Y set 32 + addr ~30 ≈ 160 VGPR
// (R11 @16 waves capped at 128 -> scratch spill, WRITE_SIZE 1GB; R10 @acc128+96 ≈ 256 -> spill).
// LDS: A 3x32K + B 2x16K = 128 KB. Per tile (NT = K/64):
//   READ_Y(t)[8 ds_read_b128] ; lgkm(8) [X(t) ready, all older retired] ; barrier#1 ;
//   STAGE_B(t+1)[2], STAGE_A(t+2)[4]   [targets last read at t-1, retired chip-wide] ;
//   MFMA X(t)[16] ; vmcnt(4) [A(t+1),B(t+1) resident; A(t+2) in flight] ; barrier#2 ;
//   READ_X(t+1)[8] ; lgkm(8) [Y(t) ready] ; MFMA Y(t)[16]
// Every MFMA consumes operands read a full phase (~400cy) earlier -> counted lgkm never
// stalls on DS latency; DS pipe and staging run under MFMA. Tail: reads/stages clamp.
// MAP: 0 natural; 1 gemm1 (bx=id>>8: all 256 CUs share one A-tile, sweep B);
//      2 gemm2 (bz=id>>6: K-chunk per id-block; active staged set ~1.5MB/XCD << L2).
// EPI 0: gelu(acc+bias[col]+sp[t>>11][col])        -> bf16 outH (unswizzled)
// EPI 1: w[t][col>>12]*gelu(acc+bias[col])         -> bf16 outH (swizzled)
// EPI 2: bz==0: acc+sum_h w*b2 -> outF ; bz>0: acc -> parts[bz-1]
template<int EPI, int MAP>
__global__ __launch_bounds__(512, 2) void k_g2(
    const bf16* __restrict__ A, long lda,
    const bf16* __restrict__ Bt, long ldb,
    int K, long kcs, int gm, int gn,
    bf16* __restrict__ outH, float* __restrict__ outF, long ldc,
    const float* __restrict__ bias,
    const float* __restrict__ aux1, const float* __restrict__ aux2,
    float* __restrict__ parts, long pStride)
{
    __shared__ __align__(16) unsigned char lsA[3][32 * 1024];
    __shared__ __align__(16) unsigned char lsB[2][16 * 1024];
    const int tid = threadIdx.x, lane = tid & 63, wid = tid >> 6;

    const int id = blockIdx.x;
    int bx, by, bz;
    if (MAP == 1) {            // gemm1: grid 2048; 256 consecutive ids share one A-tile
        bx = id >> 8; by = id & 255; bz = 0;
    } else if (MAP == 2) {     // gemm2: grid 256 = 8bx x 8by x 4bz
        bz = id >> 6; bx = id & 7; by = (id >> 3) & 7;
    } else {
        bx = id % gm; by = (id / gm) % gn; bz = id / (gm * gn);
    }
    const long tileM = (long)bx * 256;
    const long tileN = (long)by * 128;
    const bf16* Ab = A + tileM * lda + (long)bz * kcs;
    const bf16* Bb = Bt + tileN * ldb + (long)bz * kcs;

    const int wr = wid >> 1, wc = wid & 1;      // 4 x 2 waves, wave out 64x64
    const int l15 = lane & 15, kd = lane >> 4;
    const int swz = (lane & 7) << 4;

    f32x4 acc[4][4];
    #pragma unroll
    for (int m = 0; m < 4; ++m)
        #pragma unroll
        for (int n = 0; n < 4; ++n) { f32x4 z = {0.f,0.f,0.f,0.f}; acc[m][n] = z; }

    auto STAGE_A = [&](int t, int buf) {        // 32 KB: 4 gload16/thread
        const long kO = (long)t * 64;
        #pragma unroll
        for (int is = 0; is < 4; ++is) {
            const int o = is * 8192 + tid * 16;
            gload16(Ab + (long)(o >> 7) * lda + kO + ((o & 127) >> 1), lsA[buf] + o);
        }
    };
    auto STAGE_B = [&](int t, int buf) {        // 16 KB: 2 gload16/thread
        const long kO = (long)t * 64;
        #pragma unroll
        for (int is = 0; is < 2; ++is) {
            const int o = is * 8192 + tid * 16;
            gload16(Bb + (long)(o >> 7) * ldb + kO + ((o & 127) >> 1), lsB[buf] + o);
        }
    };

#define READ_SET(AV, BV, AS, BS, KK) \
    { const int kb = ((KK) * 64 + kd * 16) ^ swz; \
      _Pragma("unroll") for (int m = 0; m < 4; ++m) \
          AV[m] = *(const bf16x8*)((AS) + ((wr * 64 + m * 16 + l15) << 7) + kb); \
      _Pragma("unroll") for (int n = 0; n < 4; ++n) \
          BV[n] = *(const bf16x8*)((BS) + ((wc * 64 + n * 16 + l15) << 7) + kb); }
#define MFMA_SET(AV, BV) \
    __builtin_amdgcn_s_setprio(1); \
    _Pragma("unroll") for (int m = 0; m < 4; ++m) \
    _Pragma("unroll") for (int n = 0; n < 4; ++n) \
        acc[m][n] = __builtin_amdgcn_mfma_f32_16x16x32_bf16(AV[m], BV[n], acc[m][n], 0, 0, 0); \
    __builtin_amdgcn_s_setprio(0);
#define SBAR __builtin_amdgcn_sched_barrier(0)

    const int NT = K >> 6;                      // >= 16 at all call sites
    bf16x8 avX[4], bvX[4], avY[4], bvY[4];

    STAGE_A(0, 0); STAGE_B(0, 0); STAGE_A(1, 1);
    asm volatile("s_waitcnt vmcnt(4)" ::: "memory");   // A0,B0 resident; A1 in flight
    __builtin_amdgcn_s_barrier();
    SBAR;
    READ_SET(avX, bvX, lsA[0], lsB[0], 0);      // X(0): 8 ds_reads outstanding entering loop
    SBAR;
    for (int t = 0; t < NT; ++t) {
        const unsigned char* As  = lsA[t % 3];
        const unsigned char* Bs  = lsB[t & 1];
        const unsigned char* Asn = lsA[(t + 1) % 3];
        const unsigned char* Bsn = lsB[(t + 1) & 1];
        const int ts1 = (t + 1 < NT) ? t + 1 : t;   // clamped stage sources (tail)
        const int ts2 = (t + 2 < NT) ? t + 2 : ts1;
        // ---- READ Y(t); counted wait retires X(t) and everything older ----
        READ_SET(avY, bvY, As, Bs, 1);
        SBAR;
        asm volatile("s_waitcnt lgkmcnt(8)" ::: "memory");
        SBAR;
        __builtin_amdgcn_s_barrier();           // #1: all pre-Y reads retired chip-wide
        SBAR;
        // ---- stage into buffers last read at t-1 (retired), then MFMA X ----
        STAGE_B(ts1, (t + 1) & 1);
        STAGE_A(ts2, (t + 2) % 3);
        SBAR;
        MFMA_SET(avX, bvX);
        SBAR;
        // ---- make tile t+1 resident; A(t+2) stays in flight ----
        asm volatile("s_waitcnt vmcnt(4)" ::: "memory");
        __builtin_amdgcn_s_barrier();           // #2
        SBAR;
        // ---- READ X(t+1); counted wait retires Y(t); MFMA Y ----
        READ_SET(avX, bvX, Asn, Bsn, 0);
        SBAR;
        asm volatile("s_waitcnt lgkmcnt(8)" ::: "memory");
        SBAR;
        MFMA_SET(avY, bvY);
        SBAR;
    }

    // epilogue: C/D layout col = lane&15, row = (lane>>4)*4 + j
    const long rowBase = tileM + wr * 64;
    const int  colBase = (int)tileN + wc * 64;
    #pragma unroll
    for (int m = 0; m < 4; ++m) {
        const long r0 = rowBase + m * 16 + (kd * 4);
        #pragma unroll
        for (int n = 0; n < 4; ++n) {
            const int col = colBase + n * 16 + l15;
            #pragma unroll
            for (int j = 0; j < 4; ++j) {
                const long tk = r0 + j;
                float v = acc[m][n][j];
                if constexpr (EPI == 0) {
                    v += bias[col] + aux1[(long)(tk >> 11) * DM + col];
                    v = gelu_f(v);
                    outH[tk * ldc + col] = (bf16)v;
                } else if constexpr (EPI == 1) {
                    v += bias[col];
                    v = gelu_f(v);
                    v *= aux1[tk * NH + (col >> 12)];
                    outH[tk * ldc + (col ^ (((int)tk & 7) << 3))] = (bf16)v;
                } else {
                    if (bz == 0) {
                        float bsum = 0.f;
                        #pragma unroll
                        for (int hh = 0; hh < NH; ++hh)
                            bsum += aux1[tk * NH + hh] * aux2[(long)hh * DM + col];
                        outF[tk * ldc + col] = v + bsum;
                    } else {
                        parts[(long)(bz - 1) * pStride + tk * ldc + col] = v;
                    }
                }
            }
        }
    }
#undef READ_SET
#undef MFMA_SET
#undef SBAR
}

// ---------------- reduce: out += sum of partials ----------------
__global__ __launch_bounds__(256) void k_red(float* __restrict__ out, const float* __restrict__ parts,
                                             long pStride, int np) {
    long i = ((long)blockIdx.x * 256 + threadIdx.x) * 4;
    float4 v = *(float4*)(out + i);
    #pragma unroll
    for (int p = 0; p < NKS - 1; ++p) {
        float4 q = *(const float4*)(parts + (long)p * pStride + i);
        v.x += q.x; v.y += q.y; v.z += q.z; v.w += q.w;
    }
    *(float4*)(out + i) = v;
    (void)np;
}

extern "C" void kernel_launch(void* const* d_in, const int* in_sizes, int n_in,
                              void* d_out, int out_size, void* d_ws, size_t ws_size,
                              hipStream_t stream)
{
    const float* x  = (const float*)d_in[0];
    const float* rs = (const float*)d_in[1];
    const float* W1 = (const float*)d_in[2];
    const float* b1 = (const float*)d_in[3];
    const float* W2 = (const float*)d_in[4];
    const float* b2 = (const float*)d_in[5];
    const float* Ws = (const float*)d_in[6];
    const float* bs = (const float*)d_in[7];
    const float* Wi = (const float*)d_in[8];
    const float* bi = (const float*)d_in[9];
    const float* Wg = (const float*)d_in[10];
    const float* bg = (const float*)d_in[11];

    float* out  = (float*)d_out;                    // [8192][1024] f32
    float* wout = out + (size_t)MT * DM;            // [8192][8]   f32 (output 1)

    unsigned char* ws = (unsigned char*)d_ws;
    size_t ofs = 0;
    auto alloc = [&](size_t bytes) { void* p = ws + ofs; ofs += (bytes + 255) & ~(size_t)255; return p; };

    bf16*  xbf  = (bf16*)alloc((size_t)MT * DM * 2);          // 16.8 MB (swizzled)
    bf16*  WiT  = (bf16*)alloc((size_t)DM * DM * 2);          //  2.1 MB (swizzled)
    bf16*  g    = (bf16*)alloc((size_t)MT * DM * 2);          // 16.8 MB (linear)
    float* sp   = (float*)alloc((size_t)NB * DM * 4);         // 16 KB
    bf16*  W1T  = (bf16*)alloc((size_t)NH * DF * DM * 2);     // 67.1 MB [hf][d] swizzled
    bf16*  W2T  = (bf16*)alloc((size_t)NH * DF * DM * 2);     // 67.1 MB [d][hf] swizzled
    bf16*  hp   = (bf16*)alloc((size_t)MQ * NH * DF * 2);     // 134.2 MB [t][hf] swizzled (per quarter)
    float* part = (float*)alloc((size_t)(NKS - 1) * MQ * DM * 4);  // 25.2 MB
    const long pStride = (long)MQ * DM;

    // stage 0: conversions / transposes / projections
    k_cvtx<<<(MT * DM) / (256 * 8), 256, 0, stream>>>(x, xbf);
    k_tcvt2<<<dim3(DM / 64, DM / 64, 1), 256, 0, stream>>>(Wi, WiT, DM, DM, 0, 0);
    k_sproj2<<<dim3(DM / 16, NB), 256, 0, stream>>>(rs, Ws, bs, sp);

    // stage 1: input proj -> gelu(combined) -> g, then gate weights
    k_g2<0, 0><<<(MT / 256) * (DM / 128), 512, 0, stream>>>(
        xbf, DM, WiT, DM, DM, 0, MT / 256, DM / 128,
        g, nullptr, DM, bi, sp, nullptr, nullptr, 0);
    k_gate<<<MT / 4, 256, 0, stream>>>(g, Wg, bg, wout);

    // weight transposes
    k_tcvt2<<<dim3(DF / 64, DM / 64, NH), 256, 0, stream>>>(
        W1, W1T, DF, DM, (long)DM * DF, (long)DF * DM);
    k_tcvt2<<<dim3(DM / 64, DF / 64, NH), 256, 0, stream>>>(
        W2, W2T, DM, (long)NH * DF, (long)DF * DM, DF);

    // stage 2: per M-quarter: gemm1 (all heads) -> hp ; gemm2 (K-split 4) ; reduce
    for (int q = 0; q < MT / MQ; ++q) {
        const bf16*  xq = xbf + (size_t)q * MQ * DM;
        const float* wq = wout + (size_t)q * MQ * NH;
        float*       oq = out + (size_t)q * MQ * DM;
        k_g2<1, 1><<<(MQ / 256) * (NH * DF / 128), 512, 0, stream>>>(
            xq, DM, W1T, DM, DM, 0, MQ / 256, NH * DF / 128,
            hp, nullptr, (long)NH * DF, b1, wq, nullptr, nullptr, 0);
        k_g2<2, 2><<<(MQ / 256) * (DM / 128) * NKS, 512, 0, stream>>>(
            hp, (long)NH * DF, W2T, (long)NH * DF, KC, KC, MQ / 256, DM / 128,
            nullptr, oq, DM, nullptr, wq, b2, part, pStride);
        k_red<<<(MQ * DM) / (256 * 4), 256, 0, stream>>>(oq, part, pStride, NKS - 1);
    }
    (void)in_sizes; (void)n_in; (void)out_size;
}

// Round 13
// 1411.246 us; speedup vs baseline: 3.4377x; 1.2726x over previous
//
#include <hip/hip_runtime.h>
#include <hip/hip_bf16.h>
#include <math.h>

#define DM   1024
#define DF   4096
#define NH   8
#define NB   4
#define NS   2048
#define MT   (NB*NS)   // 8192 tokens
#define MQ   2048      // M-split quarter
#define KC   4096      // gemm2 K-split chunk
#define NKS  8         // gemm2 K-splits

typedef __bf16 bf16;
typedef __bf16 bf16x4 __attribute__((ext_vector_type(4)));
typedef __bf16 bf16x8 __attribute__((ext_vector_type(8)));
typedef float  f32x4  __attribute__((ext_vector_type(4)));

typedef __attribute__((address_space(3))) unsigned int u32_lds;
typedef const __attribute__((address_space(1))) void cv_glob;

__device__ __forceinline__ void gload16(const void* g, const void* l) {
    __builtin_amdgcn_global_load_lds(
        (cv_glob*)(unsigned long long)g,
        (u32_lds*)(unsigned int)(unsigned long long)l,
        16, 0, 0);
}

// tanh-form GELU: |gelu_tanh - gelu_erf| <= ~2e-3 absolute; 3x cheaper than erff.
__device__ __forceinline__ float gelu_f(float x) {
    float u = -1.5957691216057308f * fmaf(0.044715f * x, x * x, x);
    return x * __builtin_amdgcn_rcpf(1.f + __expf(u));
}

// SWIZZLE CONVENTION (T2, both-sides): every bf16 buffer consumed by GEMM staging is
// stored with 16B chunks permuted within each 128B (64-elem) row-block:
// elem e of row r stored at e ^ ((r&7)<<3). gload_lds copies linearly; ds_read
// XORs byte ^ ((row&7)<<4). Proven R2-R12: SQ_LDS_BANK_CONFLICT == 0.

// ---------------- x f32 -> bf16 (swizzled rows = tokens) ----------------
__global__ __launch_bounds__(256) void k_cvtx(const float* __restrict__ in, bf16* __restrict__ out) {
    long i = ((long)blockIdx.x * 256 + threadIdx.x) * 8;
    float4 a = *(const float4*)(in + i);
    float4 b = *(const float4*)(in + i + 4);
    bf16x8 o;
    o[0]=(bf16)a.x; o[1]=(bf16)a.y; o[2]=(bf16)a.z; o[3]=(bf16)a.w;
    o[4]=(bf16)b.x; o[5]=(bf16)b.y; o[6]=(bf16)b.z; o[7]=(bf16)b.w;
    long t7 = (i >> 10) & 7;
    *(bf16x8*)(out + (i ^ (t7 << 3))) = o;
}

// ---- transpose+convert+swizzle, 64x64 tile: out[c][r ^ ((c&7)<<3)] = (bf16)in[r*C+c] ----
__global__ __launch_bounds__(256) void k_tcvt2(const float* __restrict__ in, bf16* __restrict__ out,
                                               int C, long outStride, long inBatch, long outBatch) {
    __shared__ float t[64][65];
    const float* ip = in + (long)blockIdx.z * inBatch;
    bf16* op = out + (long)blockIdx.z * outBatch;
    const int c0 = blockIdx.x * 64, r0 = blockIdx.y * 64;
    const int tid = threadIdx.x;
    const int rr = tid >> 4, cc = tid & 15;
    #pragma unroll
    for (int it = 0; it < 4; ++it) {
        const int r = rr + 16 * it;
        float4 v = *(const float4*)(ip + (long)(r0 + r) * C + c0 + cc * 4);
        t[r][cc*4+0] = v.x; t[r][cc*4+1] = v.y; t[r][cc*4+2] = v.z; t[r][cc*4+3] = v.w;
    }
    __syncthreads();
    #pragma unroll
    for (int it = 0; it < 2; ++it) {
        const int oc = (tid >> 3) + 32 * it;
        const int e0 = (tid & 7) * 8;
        bf16 tmp[8];
        #pragma unroll
        for (int j = 0; j < 8; ++j) tmp[j] = (bf16)t[e0 + j][oc];
        const int rs = e0 ^ ((oc & 7) << 3);
        *(bf16x8*)(op + (long)(c0 + oc) * outStride + r0 + rs) = *(bf16x8*)tmp;
    }
}

// ---------------- state projection: sp[b][d] = rs[b]@Ws[:,d] + bs[d] ----------------
__global__ __launch_bounds__(256) void k_sproj2(const float* __restrict__ rs, const float* __restrict__ Ws,
                                                const float* __restrict__ bs, float* __restrict__ sp) {
    const int d0 = blockIdx.x * 16;
    const int ks = threadIdx.x >> 4, dd = threadIdx.x & 15;
    const float* r = rs + blockIdx.y * DM;
    float acc = 0.f;
    #pragma unroll 4
    for (int k = ks * 64; k < ks * 64 + 64; ++k)
        acc += r[k] * Ws[(long)k * DM + d0 + dd];
    __shared__ float red[256];
    red[threadIdx.x] = acc;
    __syncthreads();
    if (threadIdx.x < 16) {
        float v = bs[d0 + threadIdx.x];
        #pragma unroll
        for (int s = 0; s < 16; ++s) v += red[threadIdx.x + 16 * s];
        sp[blockIdx.y * DM + d0 + threadIdx.x] = v;
    }
}

// ---------------- gate: logits = g@Wg + bg; softmax -> wout [t][8] ----------------
__global__ __launch_bounds__(256) void k_gate(const bf16* __restrict__ g, const float* __restrict__ Wg,
                                              const float* __restrict__ bg, float* __restrict__ wout) {
    int lane = threadIdx.x & 63, wid = threadIdx.x >> 6;
    long t = (long)blockIdx.x * 4 + wid;
    const bf16* gr = g + t * DM + lane * 16;
    bf16x8 v0 = *(const bf16x8*)gr;
    bf16x8 v1 = *(const bf16x8*)(gr + 8);
    float s0=0,s1=0,s2=0,s3=0,s4=0,s5=0,s6=0,s7=0;
    #pragma unroll
    for (int i = 0; i < 16; ++i) {
        float gv = (float)((i < 8) ? v0[i] : v1[i - 8]);
        const float4* wr = (const float4*)(Wg + (long)(lane * 16 + i) * NH);
        float4 wa = wr[0], wb = wr[1];
        s0 += gv*wa.x; s1 += gv*wa.y; s2 += gv*wa.z; s3 += gv*wa.w;
        s4 += gv*wb.x; s5 += gv*wb.y; s6 += gv*wb.z; s7 += gv*wb.w;
    }
    #pragma unroll
    for (int off = 32; off >= 1; off >>= 1) {
        s0 += __shfl_xor(s0, off); s1 += __shfl_xor(s1, off);
        s2 += __shfl_xor(s2, off); s3 += __shfl_xor(s3, off);
        s4 += __shfl_xor(s4, off); s5 += __shfl_xor(s5, off);
        s6 += __shfl_xor(s6, off); s7 += __shfl_xor(s7, off);
    }
    float l0=s0+bg[0], l1=s1+bg[1], l2=s2+bg[2], l3=s3+bg[3];
    float l4=s4+bg[4], l5=s5+bg[5], l6=s6+bg[6], l7=s7+bg[7];
    float m = fmaxf(fmaxf(fmaxf(l0,l1),fmaxf(l2,l3)), fmaxf(fmaxf(l4,l5),fmaxf(l6,l7)));
    float e0=expf(l0-m), e1=expf(l1-m), e2=expf(l2-m), e3=expf(l3-m);
    float e4=expf(l4-m), e5=expf(l5-m), e6=expf(l6-m), e7=expf(l7-m);
    float inv = 1.f / (e0+e1+e2+e3+e4+e5+e6+e7);
    if (lane == 0) {
        float* wo = wout + t * NH;
        wo[0]=e0*inv; wo[1]=e1*inv; wo[2]=e2*inv; wo[3]=e3*inv;
        wo[4]=e4*inv; wo[5]=e5*inv; wo[6]=e6*inv; wo[7]=e7*inv;
    }
}

// ============ 256x256x64 bf16 GEMM — 16 waves (4/SIMD), occupancy-driven overlap ============
// R9 RESTORATION (measured best: 1415 us total). 16 waves as 4M x 4N, wave out 64x64,
// acc[4][4] f32x4 = 64 VGPR; __launch_bounds__(1024,4) -> VGPR<=128, all 16 waves resident
// (4/SIMD): read bursts and MFMA bursts of different waves co-schedule on the separate
// LDS/matrix pipes (m114 implicit overlap). Explicit read-ahead schedules (R8/R10/R11/R12)
// all measured SLOWER or spilled — K-loop exploration closed per R11 pre-commitment.
// LDS: A 3-deep x 32K + B 2-deep x 32K = 160 KB. Stages issued at tile top (B(t+1), A(t+2));
// boundary s_waitcnt vmcnt(2) keeps A(t+2)'s loads in flight across the barrier; single
// barrier/tile bounds wave skew (WAR-safe: staged buffer fully read before prior barrier).
// MAP (proven R7): 1 = gemm1 XCD-rectangle; 2 = gemm2 one-K-chunk-per-XCD.
// EPI 0: gelu(acc+bias[col]+sp[t>>11][col])        -> bf16 outH (unswizzled)
// EPI 1: w[t][col>>12]*gelu(acc+bias[col])         -> bf16 outH (swizzled)
// EPI 2: bz==0: acc+sum_h w*b2 -> outF ; bz>0: acc -> parts[bz-1]
template<int EPI, int MAP>
__global__ __launch_bounds__(1024, 4) void k_g2(
    const bf16* __restrict__ A, long lda,
    const bf16* __restrict__ Bt, long ldb,
    int K, long kcs, int gm, int gn,
    bf16* __restrict__ outH, float* __restrict__ outF, long ldc,
    const float* __restrict__ bias,
    const float* __restrict__ aux1, const float* __restrict__ aux2,
    float* __restrict__ parts, long pStride)
{
    __shared__ __align__(16) unsigned char lsA[3][32 * 1024];
    __shared__ __align__(16) unsigned char lsB[2][32 * 1024];
    const int tid = threadIdx.x, lane = tid & 63, wid = tid >> 6;

    const int id = blockIdx.x;
    int bx, by, bz;
    if (MAP == 1) {            // grid 1024 = 8bx x 128by, rounds of 256
        const int x = id & 7, j = (id >> 3) & 31, r = id >> 8;
        bx = (x & 1) * 4 + (j & 3);
        by = (x >> 1) * 8 + (j >> 2) + r * 32;
        bz = 0;
    } else if (MAP == 2) {     // grid 256 = 8bx x 4by x 8bz
        bz = id & 7;
        bx = (id >> 3) & 7;
        by = id >> 6;
    } else {
        bx = id % gm; by = (id / gm) % gn; bz = id / (gm * gn);
    }
    const long tileM = (long)bx * 256;
    const long tileN = (long)by * 256;
    const bf16* Ab = A + tileM * lda + (long)bz * kcs;
    const bf16* Bb = Bt + tileN * ldb + (long)bz * kcs;

    const int wr = wid >> 2, wc = wid & 3;      // 4 x 4 waves, wave out 64x64
    const int l15 = lane & 15, kd = lane >> 4;
    const int swz = (lane & 7) << 4;

    f32x4 acc[4][4];
    #pragma unroll
    for (int m = 0; m < 4; ++m)
        #pragma unroll
        for (int n = 0; n < 4; ++n) { f32x4 z = {0.f,0.f,0.f,0.f}; acc[m][n] = z; }

    auto STAGE_A = [&](int t) {
        const int buf = t % 3; const long kO = (long)t * 64;
        #pragma unroll
        for (int is = 0; is < 2; ++is) {
            const int o = is * 16384 + tid * 16;
            gload16(Ab + (long)(o >> 7) * lda + kO + ((o & 127) >> 1), lsA[buf] + o);
        }
    };
    auto STAGE_B = [&](int t) {
        const int buf = t & 1; const long kO = (long)t * 64;
        #pragma unroll
        for (int is = 0; is < 2; ++is) {
            const int o = is * 16384 + tid * 16;
            gload16(Bb + (long)(o >> 7) * ldb + kO + ((o & 127) >> 1), lsB[buf] + o);
        }
    };

    const int NT = K >> 6;                      // >= 16 at all call sites
    STAGE_A(0); STAGE_B(0); STAGE_A(1);
    asm volatile("s_waitcnt vmcnt(2)" ::: "memory");
    __builtin_amdgcn_s_barrier();
    for (int t = 0; t < NT; ++t) {
        const unsigned char* As = lsA[t % 3];
        const unsigned char* Bs = lsB[t & 1];
        if (t + 1 < NT) STAGE_B(t + 1);
        if (t + 2 < NT) STAGE_A(t + 2);
        #pragma unroll
        for (int kk = 0; kk < 2; ++kk) {
            const int kb = (kk * 64 + kd * 16) ^ swz;
            bf16x8 av[4], bv[4];
            #pragma unroll
            for (int m = 0; m < 4; ++m)
                av[m] = *(const bf16x8*)(As + ((wr * 64 + m * 16 + l15) << 7) + kb);
            #pragma unroll
            for (int n = 0; n < 4; ++n)
                bv[n] = *(const bf16x8*)(Bs + ((wc * 64 + n * 16 + l15) << 7) + kb);
            __builtin_amdgcn_s_setprio(1);
            #pragma unroll
            for (int m = 0; m < 4; ++m)
                #pragma unroll
                for (int n = 0; n < 4; ++n)
                    acc[m][n] = __builtin_amdgcn_mfma_f32_16x16x32_bf16(av[m], bv[n], acc[m][n], 0, 0, 0);
            __builtin_amdgcn_s_setprio(0);
        }
        if (t + 2 < NT) {
            asm volatile("s_waitcnt vmcnt(2)" ::: "memory");
        } else {
            asm volatile("s_waitcnt vmcnt(0)" ::: "memory");
        }
        __builtin_amdgcn_s_barrier();
    }

    // epilogue: C/D layout col = lane&15, row = (lane>>4)*4 + j
    const long rowBase = tileM + wr * 64;
    const int  colBase = (int)tileN + wc * 64;
    #pragma unroll
    for (int m = 0; m < 4; ++m) {
        const long r0 = rowBase + m * 16 + (kd * 4);
        #pragma unroll
        for (int n = 0; n < 4; ++n) {
            const int col = colBase + n * 16 + l15;
            #pragma unroll
            for (int j = 0; j < 4; ++j) {
                const long tk = r0 + j;
                float v = acc[m][n][j];
                if constexpr (EPI == 0) {
                    v += bias[col] + aux1[(long)(tk >> 11) * DM + col];
                    v = gelu_f(v);
                    outH[tk * ldc + col] = (bf16)v;
                } else if constexpr (EPI == 1) {
                    v += bias[col];
                    v = gelu_f(v);
                    v *= aux1[tk * NH + (col >> 12)];
                    outH[tk * ldc + (col ^ (((int)tk & 7) << 3))] = (bf16)v;
                } else {
                    if (bz == 0) {
                        float bsum = 0.f;
                        #pragma unroll
                        for (int hh = 0; hh < NH; ++hh)
                            bsum += aux1[tk * NH + hh] * aux2[(long)hh * DM + col];
                        outF[tk * ldc + col] = v + bsum;
                    } else {
                        parts[(long)(bz - 1) * pStride + tk * ldc + col] = v;
                    }
                }
            }
        }
    }
}

// ---------------- reduce: out += sum of partials ----------------
__global__ __launch_bounds__(256) void k_red(float* __restrict__ out, const float* __restrict__ parts,
                                             long pStride, int np) {
    long i = ((long)blockIdx.x * 256 + threadIdx.x) * 4;
    float4 v = *(float4*)(out + i);
    #pragma unroll
    for (int p = 0; p < NKS - 1; ++p) {
        float4 q = *(const float4*)(parts + (long)p * pStride + i);
        v.x += q.x; v.y += q.y; v.z += q.z; v.w += q.w;
    }
    *(float4*)(out + i) = v;
    (void)np;
}

extern "C" void kernel_launch(void* const* d_in, const int* in_sizes, int n_in,
                              void* d_out, int out_size, void* d_ws, size_t ws_size,
                              hipStream_t stream)
{
    const float* x  = (const float*)d_in[0];
    const float* rs = (const float*)d_in[1];
    const float* W1 = (const float*)d_in[2];
    const float* b1 = (const float*)d_in[3];
    const float* W2 = (const float*)d_in[4];
    const float* b2 = (const float*)d_in[5];
    const float* Ws = (const float*)d_in[6];
    const float* bs = (const float*)d_in[7];
    const float* Wi = (const float*)d_in[8];
    const float* bi = (const float*)d_in[9];
    const float* Wg = (const float*)d_in[10];
    const float* bg = (const float*)d_in[11];

    float* out  = (float*)d_out;                    // [8192][1024] f32
    float* wout = out + (size_t)MT * DM;            // [8192][8]   f32 (output 1)

    unsigned char* ws = (unsigned char*)d_ws;
    size_t ofs = 0;
    auto alloc = [&](size_t bytes) { void* p = ws + ofs; ofs += (bytes + 255) & ~(size_t)255; return p; };

    bf16*  xbf  = (bf16*)alloc((size_t)MT * DM * 2);          // 16.8 MB (swizzled)
    bf16*  WiT  = (bf16*)alloc((size_t)DM * DM * 2);          //  2.1 MB (swizzled)
    bf16*  g    = (bf16*)alloc((size_t)MT * DM * 2);          // 16.8 MB (linear)
    float* sp   = (float*)alloc((size_t)NB * DM * 4);         // 16 KB
    bf16*  W1T  = (bf16*)alloc((size_t)NH * DF * DM * 2);     // 67.1 MB [hf][d] swizzled
    bf16*  W2T  = (bf16*)alloc((size_t)NH * DF * DM * 2);     // 67.1 MB [d][hf] swizzled
    bf16*  hp   = (bf16*)alloc((size_t)MQ * NH * DF * 2);     // 134.2 MB [t][hf] swizzled (per quarter)
    float* part = (float*)alloc((size_t)(NKS - 1) * MQ * DM * 4);  // 58.7 MB
    const long pStride = (long)MQ * DM;

    // stage 0: conversions / transposes / projections
    k_cvtx<<<(MT * DM) / (256 * 8), 256, 0, stream>>>(x, xbf);
    k_tcvt2<<<dim3(DM / 64, DM / 64, 1), 256, 0, stream>>>(Wi, WiT, DM, DM, 0, 0);
    k_sproj2<<<dim3(DM / 16, NB), 256, 0, stream>>>(rs, Ws, bs, sp);

    // stage 1: input proj -> gelu(combined) -> g, then gate weights
    k_g2<0, 0><<<(MT / 256) * (DM / 256), 1024, 0, stream>>>(
        xbf, DM, WiT, DM, DM, 0, MT / 256, DM / 256,
        g, nullptr, DM, bi, sp, nullptr, nullptr, 0);
    k_gate<<<MT / 4, 256, 0, stream>>>(g, Wg, bg, wout);

    // weight transposes
    k_tcvt2<<<dim3(DF / 64, DM / 64, NH), 256, 0, stream>>>(
        W1, W1T, DF, DM, (long)DM * DF, (long)DF * DM);
    k_tcvt2<<<dim3(DM / 64, DF / 64, NH), 256, 0, stream>>>(
        W2, W2T, DM, (long)NH * DF, (long)DF * DM, DF);

    // stage 2: per M-quarter: gemm1 (all heads) -> hp ; gemm2 (K-split 8) ; reduce
    for (int q = 0; q < MT / MQ; ++q) {
        const bf16*  xq = xbf + (size_t)q * MQ * DM;
        const float* wq = wout + (size_t)q * MQ * NH;
        float*       oq = out + (size_t)q * MQ * DM;
        k_g2<1, 1><<<(MQ / 256) * (NH * DF / 256), 1024, 0, stream>>>(
            xq, DM, W1T, DM, DM, 0, MQ / 256, NH * DF / 256,
            hp, nullptr, (long)NH * DF, b1, wq, nullptr, nullptr, 0);
        k_g2<2, 2><<<(MQ / 256) * (DM / 256) * NKS, 1024, 0, stream>>>(
            hp, (long)NH * DF, W2T, (long)NH * DF, KC, KC, MQ / 256, DM / 256,
            nullptr, oq, DM, nullptr, wq, b2, part, pStride);
        k_red<<<(MQ * DM) / (256 * 4), 256, 0, stream>>>(oq, part, pStride, NKS - 1);
    }
    (void)in_sizes; (void)n_in; (void)out_size;
}